// Round 6
// baseline (52.480 us; speedup 1.0000x reference)
//
#include <hip/hip_runtime.h>

#define GAMMA 12.0f
#define DIM 256
#define NROWS 500
#define CW 64                               // halves per chunk slice (128 B rows)
#define NCHUNK 4                            // DIM / CW
#define ROWS_PAD 504                        // region = 504*128 B = 64512 B
#define REGION_HALVES (ROWS_PAD * CW)       // 32256
#define REGION_BYTES (REGION_HALVES * 2)    // 64512
#define STAGE_ITERS (REGION_BYTES / 1024)   // 63 wave-loads of 1024 B per chunk
#define THREADS 1024
#define WAVES 16
#define PASSES 16
#define TPB 2048                            // triplets per block
#define PIPE 4                              // software-pipeline depth (load->use = 4 passes)

typedef _Float16 h2 __attribute__((ext_vector_type(2)));

static __device__ __forceinline__ unsigned short f2h(float x) {
    _Float16 h = (_Float16)x;
    return __builtin_bit_cast(unsigned short, h);
}

// acc += |h + r - t| over one packed f16 pair, f32 accumulate via v_dot2_f32_f16
static __device__ __forceinline__ float acc_pair(unsigned uh, unsigned ur, unsigned ut, float acc) {
    h2 h = __builtin_bit_cast(h2, uh);
    h2 r = __builtin_bit_cast(h2, ur);
    h2 t = __builtin_bit_cast(h2, ut);
    h2 d = (h + r) - t;                                           // v_pk_add_f16 x2
    unsigned ad = __builtin_bit_cast(unsigned, d) & 0x7FFF7FFFu;  // packed abs
    h2 one = { (_Float16)1.0f, (_Float16)1.0f };
    return __builtin_amdgcn_fdot2(__builtin_bit_cast(h2, ad), one, acc, false);
}

// tab16 layout: [table][chunk][ROWS_PAD][CW] halves (rows >= NROWS junk, never read)
__global__ __launch_bounds__(256) void transe_convert(
    const float* __restrict__ node, const float* __restrict__ rel,
    unsigned short* __restrict__ out)
{
    const int per = NROWS * DIM;                 // 128000
    int t8 = (blockIdx.x * 256 + threadIdx.x) * 8;
    if (t8 >= 2 * per) return;
    int table = t8 >= per;
    int e = t8 - table * per;
    const float* src = table ? rel : node;
    float4 f0 = *(const float4*)(src + e);
    float4 f1 = *(const float4*)(src + e + 4);
    int row = e >> 8;
    int d = e & (DIM - 1);
    int c = d >> 6, w = d & (CW - 1);            // w multiple of 8 -> 16B aligned store
    union { unsigned short us[8]; uint4 v; } o;
    o.us[0] = f2h(f0.x); o.us[1] = f2h(f0.y); o.us[2] = f2h(f0.z); o.us[3] = f2h(f0.w);
    o.us[4] = f2h(f1.x); o.us[5] = f2h(f1.y); o.us[6] = f2h(f1.z); o.us[7] = f2h(f1.w);
    *(uint4*)(out + (size_t)(table * NCHUNK + c) * REGION_HALVES + row * CW + w) = o.v;
}

// 8 lanes per triplet, 128 B per row-chunk. h,t from double-buffered node LDS
// (wave ds_read_b128 = 8 rows x 128 B -> conflict-free). r from L2-resident global
// f16 table on the VMEM pipe. All three streams explicitly software-pipelined
// 4 deep so gather latency hides under the dot2 chains of intervening passes.
__global__ __launch_bounds__(THREADS, 4) void transe_main(
    const unsigned short* __restrict__ tab16,
    const int* __restrict__ trip,
    const float* __restrict__ node_f32,
    const float* __restrict__ rel_f32,
    float* __restrict__ out, int B)
{
    __shared__ __align__(16) unsigned short lbuf[2 * REGION_HALVES]; // 129024 B
    __shared__ int ltrip[TPB];                                       // 8192 B packed

    const int tid  = threadIdx.x;
    const int wid  = tid >> 6;
    const int lane = tid & 63;
    const int g    = lane >> 3;   // group (triplet) within wave
    const int m    = lane & 7;    // member within group
    const int moff = m * 16;
    const long base = (long)blockIdx.x * TPB;

    const char* srcb = (const char*)tab16;
    char* ldsb = (char*)lbuf;

    // ---- issue chunk-0 node staging into buf0 (async global->LDS) ----
    #pragma unroll 1
    for (int i = wid; i < STAGE_ITERS; i += WAVES) {
        const char* src = srcb + (size_t)i * 1024 + (size_t)lane * 16;
        char* dst = ldsb + i * 1024;
        __builtin_amdgcn_global_load_lds(
            (const __attribute__((address_space(1))) unsigned int*)src,
            (__attribute__((address_space(3))) unsigned int*)dst, 16, 0, 0);
    }

    // ---- pack triplets: h | r<<10 | t<<20 | oob<<30 | invalid<<31 (clamped) ----
    for (int s = tid; s < TPB; s += THREADS) {
        long j = base + s;
        unsigned pk;
        if (j < B) {
            int h = trip[3 * j], r = trip[3 * j + 1], t = trip[3 * j + 2];
            unsigned oob = ((unsigned)h >= NROWS || (unsigned)r >= NROWS || (unsigned)t >= NROWS)
                           ? (1u << 30) : 0u;
            unsigned hc = (unsigned)min(max(h, 0), NROWS - 1);
            unsigned rc = (unsigned)min(max(r, 0), NROWS - 1);
            unsigned tc = (unsigned)min(max(t, 0), NROWS - 1);
            pk = hc | (rc << 10) | (tc << 20) | oob;
        } else pk = 1u << 31;
        ltrip[s] = (int)pk;
    }
    __syncthreads();   // ltrip ready AND chunk-0 staged

    unsigned pidx[PASSES];
    #pragma unroll
    for (int p = 0; p < PASSES; ++p)
        pidx[p] = (unsigned)ltrip[wid * (8 * PASSES) + p * 8 + g];

    float acc[PASSES];
    #pragma unroll
    for (int p = 0; p < PASSES; ++p) acc[p] = 0.f;

    for (int c = 0; c < NCHUNK; ++c) {
        const char* lbase = ldsb + (c & 1) * REGION_BYTES;
        const char* relc  = srcb + (size_t)(NCHUNK + c) * REGION_BYTES;

        uint4 hs[PIPE], ts[PIPE], rs[PIPE];

        // prime r first (owns the vmcnt queue head; L2 latency starts now)
        #pragma unroll
        for (int q = 0; q < PIPE; ++q)
            rs[q] = *(const uint4*)(relc + (((pidx[q] >> 10) & 1023u) << 7) + moff);

        // stage next node chunk into the other buffer (flies during compute)
        if (c + 1 < NCHUNK) {
            const char* cb = srcb + (size_t)(c + 1) * REGION_BYTES;
            char* db = ldsb + ((c + 1) & 1) * REGION_BYTES;
            #pragma unroll 1
            for (int i = wid; i < STAGE_ITERS; i += WAVES) {
                __builtin_amdgcn_global_load_lds(
                    (const __attribute__((address_space(1))) unsigned int*)
                        (cb + (size_t)i * 1024 + (size_t)lane * 16),
                    (__attribute__((address_space(3))) unsigned int*)(db + i * 1024),
                    16, 0, 0);
            }
        }

        // prime h/t (lgkmcnt pipe, independent of the vmcnt traffic above)
        #pragma unroll
        for (int q = 0; q < PIPE; ++q) {
            hs[q] = *(const uint4*)(lbase + ((pidx[q] & 1023u) << 7) + moff);
            ts[q] = *(const uint4*)(lbase + (((pidx[q] >> 20) & 1023u) << 7) + moff);
        }

        #pragma unroll
        for (int p = 0; p < PASSES; ++p) {
            const int s = p % PIPE;            // compile-time under full unroll
            uint4 hv = hs[s], tv = ts[s], rv = rs[s];
            if (p + PIPE < PASSES) {
                unsigned pn = pidx[p + PIPE];
                rs[s] = *(const uint4*)(relc + (((pn >> 10) & 1023u) << 7) + moff);
                hs[s] = *(const uint4*)(lbase + ((pn & 1023u) << 7) + moff);
                ts[s] = *(const uint4*)(lbase + (((pn >> 20) & 1023u) << 7) + moff);
            }
            // two independent dot2 chains (chain depth 2 instead of 4)
            float a0 = acc[p], a1 = 0.f;
            a0 = acc_pair(hv.x, rv.x, tv.x, a0);
            a1 = acc_pair(hv.y, rv.y, tv.y, a1);
            a0 = acc_pair(hv.z, rv.z, tv.z, a0);
            a1 = acc_pair(hv.w, rv.w, tv.w, a1);
            acc[p] = a0 + a1;
        }

        __syncthreads();  // all waves done reading buf[c&1]; stage(c+1) drained pre-barrier
    }

    // reduce over the 8 members of each group; member 0 writes
    #pragma unroll
    for (int p = 0; p < PASSES; ++p) {
        float a = acc[p];
        a += __shfl_xor(a, 1, 64);
        a += __shfl_xor(a, 2, 64);
        a += __shfl_xor(a, 4, 64);
        if (m == 0) {
            unsigned pk = pidx[p];
            int slot = wid * (8 * PASSES) + p * 8 + g;
            long j = base + slot;
            if (!(pk >> 30)) {
                out[j] = GAMMA - a;
            } else if (!(pk >> 31)) {   // oob index: exact f32 fallback (never hit here)
                int hh = trip[3 * j], rr = trip[3 * j + 1], tt = trip[3 * j + 2];
                float s = 0.f;
                for (int d = 0; d < DIM; ++d)
                    s += fabsf(node_f32[(size_t)hh * DIM + d] + rel_f32[(size_t)rr * DIM + d]
                             - node_f32[(size_t)tt * DIM + d]);
                out[j] = GAMMA - s;
            }
        }
    }
}

// Round-1 fallback (only if d_ws is too small for the f16 tables)
__global__ __launch_bounds__(256) void transe_direct(
    const float* __restrict__ node_emb,
    const float* __restrict__ rel_emb,
    const int*   __restrict__ triplets,
    float*       __restrict__ out, int B)
{
    const int wave = blockIdx.x * (blockDim.x >> 6) + (threadIdx.x >> 6);
    const int lane = threadIdx.x & 63;
    if (wave >= B) return;
    const int h_idx = triplets[wave * 3 + 0];
    const int r_idx = triplets[wave * 3 + 1];
    const int t_idx = triplets[wave * 3 + 2];
    const float4 h = ((const float4*)(node_emb + (size_t)h_idx * DIM))[lane];
    const float4 r = ((const float4*)(rel_emb  + (size_t)r_idx * DIM))[lane];
    const float4 t = ((const float4*)(node_emb + (size_t)t_idx * DIM))[lane];
    float s = fabsf(h.x + r.x - t.x) + fabsf(h.y + r.y - t.y)
            + fabsf(h.z + r.z - t.z) + fabsf(h.w + r.w - t.w);
    #pragma unroll
    for (int off = 32; off > 0; off >>= 1) s += __shfl_down(s, off, 64);
    if (lane == 0) out[wave] = GAMMA - s;
}

extern "C" void kernel_launch(void* const* d_in, const int* in_sizes, int n_in,
                              void* d_out, int out_size, void* d_ws, size_t ws_size,
                              hipStream_t stream) {
    const float* node_emb = (const float*)d_in[0];
    const float* rel_emb  = (const float*)d_in[1];
    const int*   triplets = (const int*)d_in[2];
    float*       out      = (float*)d_out;
    const int B = out_size;

    const size_t ws_needed = (size_t)2 * NCHUNK * REGION_HALVES * sizeof(unsigned short); // 516096
    if (ws_size < ws_needed) {
        const int grid = (B + 3) / 4;
        transe_direct<<<grid, 256, 0, stream>>>(node_emb, rel_emb, triplets, out, B);
        return;
    }

    unsigned short* tab16 = (unsigned short*)d_ws;

    const int conv_threads = 2 * NROWS * DIM / 8;   // 32000
    transe_convert<<<(conv_threads + 255) / 256, 256, 0, stream>>>(node_emb, rel_emb, tab16);

    const int grid = (B + TPB - 1) / TPB;           // 245 blocks, 1/CU
    transe_main<<<grid, THREADS, 0, stream>>>(tab16, triplets, node_emb, rel_emb, out, B);
}